// Round 11
// baseline (310.878 us; speedup 1.0000x reference)
//
#include <hip/hip_runtime.h>
#include <hip/hip_bf16.h>
#include <math.h>

#define B 2
#define N 2048
#define D 256
#define H 4
#define DH 64
#define D2 512
#define BH 8
#define BKP 40

static constexpr float ALPHA_DIV = 0.01f;
static constexpr float LN_EPS = 1e-5f;
static constexpr float SCL = 0.35355339059327373f; // 64^-0.25

typedef __attribute__((ext_vector_type(4))) float f32x4;
typedef __attribute__((ext_vector_type(8))) short s16x8;

// =======================================================================
// projection: qkv = x @ WcT^T + cb. qk cols -> qkv; v cols -> vT transposed;
// block x==0 also writes x bf16 into xc left half. grid (8, 32, 2)
// =======================================================================
__global__ __launch_bounds__(256) void proj_kernel(
    const float* __restrict__ x0, const float* __restrict__ x1,
    const __hip_bfloat16* __restrict__ WcT, const float* __restrict__ cb,
    __hip_bfloat16* __restrict__ qkv0, __hip_bfloat16* __restrict__ qkv1,
    __hip_bfloat16* __restrict__ vT,
    __hip_bfloat16* __restrict__ xc0, __hip_bfloat16* __restrict__ xc1)
{
    __shared__ __hip_bfloat16 As[128][BKP];
    __shared__ __hip_bfloat16 Ws[64][BKP];
    __shared__ __hip_bfloat16 T[128][72];
    const int z = blockIdx.z;
    const float* x = z ? x1 : x0;
    __hip_bfloat16* qkv = z ? qkv1 : qkv0;
    __hip_bfloat16* xc = z ? xc1 : xc0;
    const int rowBase = blockIdx.y * 128;
    const int colBase = blockIdx.x * 64;
    const int tid = threadIdx.x;
    const int lane = tid & 63, wid = tid >> 6;
    const int wr = wid >> 1, wc = wid & 1;
    const int lr = lane & 15, g = lane >> 4, lk = g * 8;

    f32x4 acc[4][2] = {};
    for (int k0 = 0; k0 < D; k0 += 32) {
#pragma unroll
        for (int c = 0; c < 2; c++) {
            int e = (tid + c * 256) * 8;
            int r = e >> 5, kk = e & 31;
            const float4 v0 = *(const float4*)&x[(size_t)(rowBase + r) * D + k0 + kk];
            const float4 v1 = *(const float4*)&x[(size_t)(rowBase + r) * D + k0 + kk + 4];
            union { s16x8 v; __hip_bfloat16 hh[8]; } u;
            u.hh[0] = __float2bfloat16(v0.x); u.hh[1] = __float2bfloat16(v0.y);
            u.hh[2] = __float2bfloat16(v0.z); u.hh[3] = __float2bfloat16(v0.w);
            u.hh[4] = __float2bfloat16(v1.x); u.hh[5] = __float2bfloat16(v1.y);
            u.hh[6] = __float2bfloat16(v1.z); u.hh[7] = __float2bfloat16(v1.w);
            *(s16x8*)&As[r][kk] = u.v;
            if (colBase == 0)
                *(s16x8*)&xc[(size_t)(rowBase + r) * D2 + k0 + kk] = u.v;
        }
        {
            int e = tid * 8;
            int n = e >> 5, kk = e & 31;
            *(s16x8*)&Ws[n][kk] = *(const s16x8*)&WcT[(size_t)(colBase + n) * D + k0 + kk];
        }
        __syncthreads();
        s16x8 a[4], b[2];
#pragma unroll
        for (int i = 0; i < 4; i++) a[i] = *(const s16x8*)&As[wr * 64 + i * 16 + lr][lk];
#pragma unroll
        for (int j = 0; j < 2; j++) b[j] = *(const s16x8*)&Ws[wc * 32 + j * 16 + lr][lk];
#pragma unroll
        for (int i = 0; i < 4; i++)
#pragma unroll
            for (int j = 0; j < 2; j++)
                acc[i][j] = __builtin_amdgcn_mfma_f32_16x16x32_bf16(a[i], b[j], acc[i][j], 0, 0, 0);
        __syncthreads();
    }

    if (colBase < 256) {
#pragma unroll
        for (int i = 0; i < 4; i++)
#pragma unroll
            for (int j = 0; j < 2; j++) {
                int col = colBase + wc * 32 + j * 16 + lr;
                float bval = cb[col];
#pragma unroll
                for (int t = 0; t < 4; t++) {
                    int row = rowBase + wr * 64 + i * 16 + g * 4 + t;
                    qkv[(size_t)row * D2 + col] = __float2bfloat16(acc[i][j][t] + bval);
                }
            }
    } else {
#pragma unroll
        for (int i = 0; i < 4; i++)
#pragma unroll
            for (int j = 0; j < 2; j++) {
                int cl = wc * 32 + j * 16 + lr;
                float bval = cb[colBase + cl];
#pragma unroll
                for (int t = 0; t < 4; t++)
                    T[wr * 64 + i * 16 + g * 4 + t][cl] = __float2bfloat16(acc[i][j][t] + bval);
            }
        __syncthreads();
        int hh = (colBase - 256) >> 6;
        int b_ = rowBase >> 11, n0 = rowBase & (N - 1);
        int slot = (z ? 0 : 8) + b_ * H + hh;
        int dh = tid >> 2, nn0 = (tid & 3) * 32;
        alignas(16) __hip_bfloat16 tmp[32];
#pragma unroll
        for (int u = 0; u < 32; u++) tmp[u] = T[nn0 + u][dh];
        __hip_bfloat16* dst = vT + ((size_t)slot * DH + dh) * N + n0 + nn0;
#pragma unroll
        for (int u8 = 0; u8 < 4; u8++)
            *(s16x8*)&dst[u8 * 8] = *(s16x8*)&tmp[u8 * 8];
    }
}

// ---------------- weight prep (transposes + Wo@W1_bot fold, one kernel) ----------------
__device__ void transpose_tile(const float* W, int ldw, __hip_bfloat16* WT, int ldt,
                               int n0, int k0, float scale)
{
    __shared__ float T[32][33];
    int t = threadIdx.x;
    int r = t >> 3, c = (t & 7) * 4;
    float4 v = *(const float4*)&W[(size_t)(k0 + r) * ldw + n0 + c];
    T[r][c] = v.x; T[r][c + 1] = v.y; T[r][c + 2] = v.z; T[r][c + 3] = v.w;
    __syncthreads();
    __hip_bfloat16* dst = &WT[(size_t)(n0 + r) * ldt + k0 + c];
    dst[0] = __float2bfloat16(T[c][r] * scale);
    dst[1] = __float2bfloat16(T[c + 1][r] * scale);
    dst[2] = __float2bfloat16(T[c + 2][r] * scale);
    dst[3] = __float2bfloat16(T[c + 3][r] * scale);
}

__global__ __launch_bounds__(256) void prep_weights(
    const float* Wqk, const float* Wv, const float* Wo,
    const float* W1, const float* W2,
    const float* bqk, const float* bv, const float* b1, const float* bo,
    __hip_bfloat16* WcT, __hip_bfloat16* W1cT, __hip_bfloat16* W2T,
    float* cb, float* cb2)
{
    int blk = blockIdx.x;
    if (blk < 64) {
        int nT = blk & 7, kT = blk >> 3;
        transpose_tile(Wqk, 256, WcT, 256, nT * 32, kT * 32, SCL);
    } else if (blk < 128) {
        int t = blk - 64; int nT = t & 7, kT = t >> 3;
        transpose_tile(Wv, 256, WcT + 256 * 256, 256, nT * 32, kT * 32, 1.f);
    } else if (blk < 256) {
        int t = blk - 128; int nT = t & 15, kT = t >> 4;   // W1 top half: k < 256
        transpose_tile(W1, 512, W1cT, 512, nT * 32, kT * 32, 1.f);
    } else if (blk < 384) {
        int t = blk - 256; int nT = t & 7, kT = t >> 3;
        transpose_tile(W2, 256, W2T, 512, nT * 32, kT * 32, 1.f);
    } else if (blk < 416) {
        // F = Wo @ W1_bot  ->  W1cT[n][256+k] = F[k][n]
        __shared__ float As[64][17];
        __shared__ float Bs[64][17];
        int t2 = blk - 384;
        int n0 = (t2 & 7) * 64, k0 = (t2 >> 3) * 64;
        int tx = threadIdx.x & 15, ty = threadIdx.x >> 4;
        float acc[4][4] = {};
        for (int c0 = 0; c0 < 256; c0 += 16) {
#pragma unroll
            for (int it = 0; it < 4; it++) {
                int idx = threadIdx.x + it * 256;
                int n = idx & 63, c = idx >> 6;
                As[n][c] = W1[(size_t)(256 + c0 + c) * 512 + n0 + n];
            }
#pragma unroll
            for (int it = 0; it < 4; it++) {
                int idx = threadIdx.x + it * 256;
                int k = idx >> 4, c = idx & 15;
                Bs[k][c] = Wo[(size_t)(k0 + k) * 256 + c0 + c];
            }
            __syncthreads();
#pragma unroll
            for (int c = 0; c < 16; c++) {
                float av[4], bv2[4];
#pragma unroll
                for (int i = 0; i < 4; i++) av[i] = As[ty + i * 16][c];
#pragma unroll
                for (int j = 0; j < 4; j++) bv2[j] = Bs[tx + j * 16][c];
#pragma unroll
                for (int i = 0; i < 4; i++)
#pragma unroll
                    for (int j = 0; j < 4; j++) acc[i][j] += av[i] * bv2[j];
            }
            __syncthreads();
        }
#pragma unroll
        for (int i = 0; i < 4; i++)
#pragma unroll
            for (int j = 0; j < 4; j++)
                W1cT[(size_t)(n0 + ty + i * 16) * 512 + 256 + k0 + tx + j * 16] =
                    __float2bfloat16(acc[i][j]);
    } else if (blk < 418) {
        int n = (blk - 416) * 256 + threadIdx.x;
        float s = b1[n];
        for (int c = 0; c < 256; c++) s += bo[c] * W1[(size_t)(256 + c) * 512 + n];
        cb2[n] = s;
    } else {
        int t = threadIdx.x;
        cb[t] = SCL * bqk[t];
        cb[256 + t] = bv[t];
    }
}

// =======================================================================
// fused two-pass attention, BARRIER-FREE main loops:
// K and V fragments loaded per-lane from global (L2-resident panels);
// Pfb is wave-local (each wave owns rows w*16..w*16+15) -> no cross-wave
// sync in either pass. 512 blocks (dir,bh,64 q-rows), XCD-swizzled.
// =======================================================================
__global__ __launch_bounds__(256) void fused_attn_av(
    const __hip_bfloat16* __restrict__ qkv0, const __hip_bfloat16* __restrict__ qkv1,
    const float* __restrict__ cm0, const float* __restrict__ cm1,
    const __hip_bfloat16* __restrict__ vT,
    float* __restrict__ attn01, float* __restrict__ attn10,
    __hip_bfloat16* __restrict__ xc0, __hip_bfloat16* __restrict__ xc1)
{
    __shared__ __hip_bfloat16 Pfb[64][136];   // wave-local 16-row stripes
    __shared__ float okm[2048];

    const int tid = threadIdx.x;
    int l = blockIdx.x;
    int xcd = l & 7, idx = l >> 3;
    int zz = xcd * 2 + (idx >> 5);
    int xb = idx & 31;
    int dir = zz >> 3, bh = zz & 7;
    int b = bh >> 2, h = bh & 3;

    const __hip_bfloat16* qQ = (dir ? qkv1 : qkv0) + (size_t)b * N * D2 + h * DH;
    const __hip_bfloat16* qK = (dir ? qkv0 : qkv1) + (size_t)b * N * D2 + h * DH;
    const float* cmK = (dir ? cm0 : cm1) + b * N;
    const __hip_bfloat16* vslot = vT + (size_t)((dir ? 8 : 0) + bh) * DH * N;
    float* attnOut = (dir ? attn10 : attn01) + (size_t)bh * N * N;
    __hip_bfloat16* mOut = (dir ? xc1 : xc0) + (size_t)b * N * D2 + 256 + h * DH;

    const int i0 = xb * 64;
    const int lane = tid & 63, w = tid >> 6;
    const int lr = lane & 15, g = lane >> 4;

    // Q fragments in registers (row = w*16+lr)
    s16x8 a0 = *(const s16x8*)&qQ[(size_t)(i0 + w * 16 + lr) * D2 + g * 8];
    s16x8 a1 = *(const s16x8*)&qQ[(size_t)(i0 + w * 16 + lr) * D2 + 32 + g * 8];

    // key mask staged once (only cross-wave LDS use -> one barrier)
#pragma unroll
    for (int it = 0; it < 8; it++) okm[tid + it * 256] = cmK[tid + it * 256];
    __syncthreads();

    // ---------------- PASS 1: row sums (no max), barrier-free ----------------
    float sp[4] = { 0.f, 0.f, 0.f, 0.f };
    for (int jt = 0; jt < 16; jt++) {
        const int k0 = jt * 128;
        f32x4 accs[8] = {};
#pragma unroll
        for (int j = 0; j < 8; j++) {
            const __hip_bfloat16* kr = &qK[(size_t)(k0 + j * 16 + lr) * D2];
            s16x8 bb0 = *(const s16x8*)&kr[g * 8];
            s16x8 bb1 = *(const s16x8*)&kr[32 + g * 8];
            accs[j] = __builtin_amdgcn_mfma_f32_16x16x32_bf16(a0, bb0, accs[j], 0, 0, 0);
            accs[j] = __builtin_amdgcn_mfma_f32_16x16x32_bf16(a1, bb1, accs[j], 0, 0, 0);
        }
#pragma unroll
        for (int j = 0; j < 8; j++) {
            bool ok = okm[k0 + j * 16 + lr] >= ALPHA_DIV;
#pragma unroll
            for (int t = 0; t < 4; t++)
                if (ok) sp[t] += __expf(accs[j][t]);
        }
    }
    float inv[4];
#pragma unroll
    for (int t = 0; t < 4; t++) {
#pragma unroll
        for (int off = 1; off <= 8; off <<= 1) sp[t] += __shfl_xor(sp[t], off);
        inv[t] = 1.f / sp[t];
    }

    // ---------------- PASS 2: barrier-free (Pfb wave-local) ----------------
    f32x4 acc_o[4] = {};
    for (int jt = 0; jt < 16; jt++) {
        const int k0 = jt * 128;

        f32x4 accs[8] = {};
#pragma unroll
        for (int j = 0; j < 8; j++) {
            const __hip_bfloat16* kr = &qK[(size_t)(k0 + j * 16 + lr) * D2];
            s16x8 bb0 = *(const s16x8*)&kr[g * 8];
            s16x8 bb1 = *(const s16x8*)&kr[32 + g * 8];
            accs[j] = __builtin_amdgcn_mfma_f32_16x16x32_bf16(a0, bb0, accs[j], 0, 0, 0);
            accs[j] = __builtin_amdgcn_mfma_f32_16x16x32_bf16(a1, bb1, accs[j], 0, 0, 0);
        }

        // normalize -> own Pfb stripe (rows w*16..w*16+15)
#pragma unroll
        for (int j = 0; j < 8; j++) {
            bool ok = okm[k0 + j * 16 + lr] >= ALPHA_DIV;
#pragma unroll
            for (int t = 0; t < 4; t++) {
                float pv = ok ? __expf(accs[j][t]) * inv[t] : 0.f;
                Pfb[w * 16 + g * 4 + t][j * 16 + lr] = __float2bfloat16(pv);
            }
        }

        // attn write, wave-local: lane -> row w*16+(lane>>2), cols (lane&3)*32..+31
        {
            int r = w * 16 + (lane >> 2), cs = (lane & 3) * 32;
#pragma unroll
            for (int u = 0; u < 4; u++) {
                union { s16x8 v; __hip_bfloat16 hh[8]; } uu;
                uu.v = *(const s16x8*)&Pfb[r][cs + u * 8];
                float4 o0, o1;
                o0.x = __bfloat162float(uu.hh[0]); o0.y = __bfloat162float(uu.hh[1]);
                o0.z = __bfloat162float(uu.hh[2]); o0.w = __bfloat162float(uu.hh[3]);
                o1.x = __bfloat162float(uu.hh[4]); o1.y = __bfloat162float(uu.hh[5]);
                o1.z = __bfloat162float(uu.hh[6]); o1.w = __bfloat162float(uu.hh[7]);
                *(float4*)&attnOut[(size_t)(i0 + r) * N + k0 + cs + u * 8] = o0;
                *(float4*)&attnOut[(size_t)(i0 + r) * N + k0 + cs + u * 8 + 4] = o1;
            }
        }

        // P@V, wave-local Pfb reads; V fragments from global (L2-resident)
#pragma unroll
        for (int ks = 0; ks < 4; ks++) {
            s16x8 pa = *(const s16x8*)&Pfb[w * 16 + lr][ks * 32 + g * 8];
#pragma unroll
            for (int j = 0; j < 4; j++) {
                s16x8 vb = *(const s16x8*)&vslot[(size_t)(j * 16 + lr) * N + k0 + ks * 32 + g * 8];
                acc_o[j] = __builtin_amdgcn_mfma_f32_16x16x32_bf16(pa, vb, acc_o[j], 0, 0, 0);
            }
        }
    }

    // epilogue: O -> xc right half via LDS (reuse Pfb; cross-wave -> barrier)
    __syncthreads();
    __hip_bfloat16* Ob = (__hip_bfloat16*)Pfb;
#pragma unroll
    for (int j = 0; j < 4; j++)
#pragma unroll
        for (int t = 0; t < 4; t++)
            Ob[(w * 16 + g * 4 + t) * 136 + j * 16 + lr] = __float2bfloat16(acc_o[j][t]);
    __syncthreads();
    {
        int row = tid >> 2, c0 = (tid & 3) * 16;
        *(s16x8*)&mOut[(size_t)(i0 + row) * D2 + c0]     = *(const s16x8*)&Ob[row * 136 + c0];
        *(s16x8*)&mOut[(size_t)(i0 + row) * D2 + c0 + 8] = *(const s16x8*)&Ob[row * 136 + c0 + 8];
    }
}

// =======================================================================
// FFN tail fused: h = xc@W1cT + cb2; LN; GELU; out = Hs@W2T + b2 + x.
// One block = 32 rows of one stream. grid (128, 2).
// =======================================================================
#define HS_LD 528
__global__ __launch_bounds__(256) void ffn_tail(
    const __hip_bfloat16* __restrict__ xc0, const __hip_bfloat16* __restrict__ xc1,
    const __hip_bfloat16* __restrict__ W1T, const float* __restrict__ b1,
    const float* __restrict__ lng, const float* __restrict__ lnb,
    const __hip_bfloat16* __restrict__ W2T, const float* __restrict__ b2,
    const float* __restrict__ x0, const float* __restrict__ x1,
    float* __restrict__ out0, float* __restrict__ out1)
{
    __shared__ __hip_bfloat16 As[32][BKP];
    __shared__ __hip_bfloat16 WH[512 * BKP];
    __shared__ float redS[4][32], redQ[4][32];

    const __hip_bfloat16* xc = blockIdx.y ? xc1 : xc0;
    const float* xres = blockIdx.y ? x1 : x0;
    float* outp = blockIdx.y ? out1 : out0;
    const int rowBase = blockIdx.x * 32;
    const int tid = threadIdx.x;
    const int w = tid >> 6, lane = tid & 63;
    const int lr = lane & 15, g = lane >> 4, lk = g * 8;

    f32x4 acc[2][8] = {};
    for (int k0 = 0; k0 < D2; k0 += 32) {
        if (tid < 128) {
            int e = tid * 8;
            int r = e >> 5, kk = e & 31;
            *(s16x8*)&As[r][kk] = *(const s16x8*)&xc[(size_t)(rowBase + r) * D2 + k0 + kk];
        }
#pragma unroll
        for (int c = 0; c < 8; c++) {
            int e = (tid + c * 256) * 8;
            int n = e >> 5, kk = e & 31;
            *(s16x8*)&WH[n * BKP + kk] = *(const s16x8*)&W1T[(size_t)n * D2 + k0 + kk];
        }
        __syncthreads();
        s16x8 a[2], b[8];
#pragma unroll
        for (int i = 0; i < 2; i++) a[i] = *(const s16x8*)&As[i * 16 + lr][lk];
#pragma unroll
        for (int j = 0; j < 8; j++) b[j] = *(const s16x8*)&WH[(w * 128 + j * 16 + lr) * BKP + lk];
#pragma unroll
        for (int i = 0; i < 2; i++)
#pragma unroll
            for (int j = 0; j < 8; j++)
                acc[i][j] = __builtin_amdgcn_mfma_f32_16x16x32_bf16(a[i], b[j], acc[i][j], 0, 0, 0);
        __syncthreads();
    }

    float cols_b[8];
#pragma unroll
    for (int j = 0; j < 8; j++) cols_b[j] = b1[w * 128 + j * 16 + lr];
#pragma unroll
    for (int i = 0; i < 2; i++) {
#pragma unroll
        for (int t = 0; t < 4; t++) {
            float s = 0.f, q = 0.f;
#pragma unroll
            for (int j = 0; j < 8; j++) {
                float hv = acc[i][j][t] + cols_b[j];
                acc[i][j][t] = hv;
                s += hv; q += hv * hv;
            }
#pragma unroll
            for (int off = 1; off <= 8; off <<= 1) {
                s += __shfl_xor(s, off);
                q += __shfl_xor(q, off);
            }
            if (lr == 0) {
                int row = i * 16 + g * 4 + t;
                redS[w][row] = s; redQ[w][row] = q;
            }
        }
    }
    __syncthreads();

    __hip_bfloat16* Hs = WH;
    float gcol[8], bcol[8];
#pragma unroll
    for (int j = 0; j < 8; j++) {
        gcol[j] = lng[w * 128 + j * 16 + lr];
        bcol[j] = lnb[w * 128 + j * 16 + lr];
    }
#pragma unroll
    for (int i = 0; i < 2; i++) {
#pragma unroll
        for (int t = 0; t < 4; t++) {
            int row = i * 16 + g * 4 + t;
            float sum = redS[0][row] + redS[1][row] + redS[2][row] + redS[3][row];
            float sq  = redQ[0][row] + redQ[1][row] + redQ[2][row] + redQ[3][row];
            float mu = sum * (1.f / 512.f);
            float var = sq * (1.f / 512.f) - mu * mu;
            float rstd = rsqrtf(var + LN_EPS);
#pragma unroll
            for (int j = 0; j < 8; j++) {
                float y = (acc[i][j][t] - mu) * rstd * gcol[j] + bcol[j];
                float ge = 0.5f * y * (1.f + erff(y * 0.70710678118654752f));
                Hs[row * HS_LD + w * 128 + j * 16 + lr] = __float2bfloat16(ge);
            }
        }
    }
    __syncthreads();

    f32x4 acc2[2][4] = {};
    for (int k0 = 0; k0 < D2; k0 += 32) {
        s16x8 a[2], b[4];
#pragma unroll
        for (int i = 0; i < 2; i++)
            a[i] = *(const s16x8*)&Hs[(i * 16 + lr) * HS_LD + k0 + lk];
#pragma unroll
        for (int j = 0; j < 4; j++)
            b[j] = *(const s16x8*)&W2T[(size_t)(w * 64 + j * 16 + lr) * D2 + k0 + lk];
#pragma unroll
        for (int i = 0; i < 2; i++)
#pragma unroll
            for (int j = 0; j < 4; j++)
                acc2[i][j] = __builtin_amdgcn_mfma_f32_16x16x32_bf16(a[i], b[j], acc2[i][j], 0, 0, 0);
    }
#pragma unroll
    for (int i = 0; i < 2; i++) {
#pragma unroll
        for (int j = 0; j < 4; j++) {
            int col = w * 64 + j * 16 + lr;
            float bval = b2[col];
#pragma unroll
            for (int t = 0; t < 4; t++) {
                int row = rowBase + i * 16 + g * 4 + t;
                outp[(size_t)row * D + col] =
                    acc2[i][j][t] + bval + xres[(size_t)row * D + col];
            }
        }
    }
}

extern "C" void kernel_launch(void* const* d_in, const int* in_sizes, int n_in,
                              void* d_out, int out_size, void* d_ws, size_t ws_size,
                              hipStream_t stream) {
    const float* x0  = (const float*)d_in[0];
    const float* x1  = (const float*)d_in[1];
    const float* cm0 = (const float*)d_in[2];
    const float* cm1 = (const float*)d_in[3];
    const float* Wqk = (const float*)d_in[4]; const float* bqk = (const float*)d_in[5];
    const float* Wv  = (const float*)d_in[6]; const float* bv  = (const float*)d_in[7];
    const float* Wo  = (const float*)d_in[8]; const float* bo  = (const float*)d_in[9];
    const float* W1  = (const float*)d_in[10]; const float* b1 = (const float*)d_in[11];
    const float* lng = (const float*)d_in[12]; const float* lnb = (const float*)d_in[13];
    const float* W2  = (const float*)d_in[14]; const float* b2 = (const float*)d_in[15];

    float* out = (float*)d_out;
    char* p = (char*)d_ws;

    const size_t XSZ = (size_t)B * N * D;
    auto alloc = [&](size_t bytes) { char* r = p; p += (bytes + 255) & ~255ull; return r; };
    __hip_bfloat16* qkv0 = (__hip_bfloat16*)alloc((size_t)B * N * D2 * 2);
    __hip_bfloat16* qkv1 = (__hip_bfloat16*)alloc((size_t)B * N * D2 * 2);
    __hip_bfloat16* vT   = (__hip_bfloat16*)alloc((size_t)16 * DH * N * 2);
    __hip_bfloat16* xc0  = (__hip_bfloat16*)alloc((size_t)B * N * D2 * 2);
    __hip_bfloat16* xc1  = (__hip_bfloat16*)alloc((size_t)B * N * D2 * 2);
    __hip_bfloat16* WcT  = (__hip_bfloat16*)alloc(512 * 256 * 2);
    __hip_bfloat16* W1cT = (__hip_bfloat16*)alloc(512 * 512 * 2);
    __hip_bfloat16* W2T  = (__hip_bfloat16*)alloc(256 * 512 * 2);
    float* cb            = (float*)alloc(512 * 4);
    float* cb2           = (float*)alloc(512 * 4);

    float* out0 = out;
    float* out1 = out + XSZ;
    float* attn01 = out + 2 * XSZ;
    float* attn10 = attn01 + (size_t)BH * N * N;

    dim3 blk(256);

    prep_weights<<<419, blk, 0, stream>>>(Wqk, Wv, Wo, W1, W2, bqk, bv, b1, bo,
                                          WcT, W1cT, W2T, cb, cb2);

    proj_kernel<<<dim3(8, 32, 2), blk, 0, stream>>>(
        x0, x1, WcT, cb, qkv0, qkv1, vT, xc0, xc1);

    fused_attn_av<<<512, blk, 0, stream>>>(qkv0, qkv1, cm0, cm1, vT,
        attn01, attn10, xc0, xc1);

    ffn_tail<<<dim3(128, 2), blk, 0, stream>>>(
        xc0, xc1, W1cT, cb2, lng, lnb, W2T, b2, x0, x1, out0, out1);
}

// Round 12
// 178.409 us; speedup vs baseline: 1.7425x; 1.7425x over previous
//
#include <hip/hip_runtime.h>
#include <hip/hip_bf16.h>
#include <math.h>

#define B 2
#define N 2048
#define D 256
#define H 4
#define DH 64
#define D2 512
#define BH 8
#define BKP 40

static constexpr float ALPHA_DIV = 0.01f;
static constexpr float LN_EPS = 1e-5f;
static constexpr float SCL = 0.35355339059327373f; // 64^-0.25

typedef __attribute__((ext_vector_type(4))) float f32x4;
typedef __attribute__((ext_vector_type(8))) short s16x8;

// =======================================================================
// projection: qkv = x @ WcT^T + cb. qk cols -> qkv; v cols -> vT transposed;
// block x==0 also writes x bf16 into xc left half. grid (8, 32, 2)
// =======================================================================
__global__ __launch_bounds__(256) void proj_kernel(
    const float* __restrict__ x0, const float* __restrict__ x1,
    const __hip_bfloat16* __restrict__ WcT, const float* __restrict__ cb,
    __hip_bfloat16* __restrict__ qkv0, __hip_bfloat16* __restrict__ qkv1,
    __hip_bfloat16* __restrict__ vT,
    __hip_bfloat16* __restrict__ xc0, __hip_bfloat16* __restrict__ xc1)
{
    __shared__ __hip_bfloat16 As[128][BKP];
    __shared__ __hip_bfloat16 Ws[64][BKP];
    __shared__ __hip_bfloat16 T[128][72];
    const int z = blockIdx.z;
    const float* x = z ? x1 : x0;
    __hip_bfloat16* qkv = z ? qkv1 : qkv0;
    __hip_bfloat16* xc = z ? xc1 : xc0;
    const int rowBase = blockIdx.y * 128;
    const int colBase = blockIdx.x * 64;
    const int tid = threadIdx.x;
    const int lane = tid & 63, wid = tid >> 6;
    const int wr = wid >> 1, wc = wid & 1;
    const int lr = lane & 15, g = lane >> 4, lk = g * 8;

    f32x4 acc[4][2] = {};
    for (int k0 = 0; k0 < D; k0 += 32) {
#pragma unroll
        for (int c = 0; c < 2; c++) {
            int e = (tid + c * 256) * 8;
            int r = e >> 5, kk = e & 31;
            const float4 v0 = *(const float4*)&x[(size_t)(rowBase + r) * D + k0 + kk];
            const float4 v1 = *(const float4*)&x[(size_t)(rowBase + r) * D + k0 + kk + 4];
            union { s16x8 v; __hip_bfloat16 hh[8]; } u;
            u.hh[0] = __float2bfloat16(v0.x); u.hh[1] = __float2bfloat16(v0.y);
            u.hh[2] = __float2bfloat16(v0.z); u.hh[3] = __float2bfloat16(v0.w);
            u.hh[4] = __float2bfloat16(v1.x); u.hh[5] = __float2bfloat16(v1.y);
            u.hh[6] = __float2bfloat16(v1.z); u.hh[7] = __float2bfloat16(v1.w);
            *(s16x8*)&As[r][kk] = u.v;
            if (colBase == 0)
                *(s16x8*)&xc[(size_t)(rowBase + r) * D2 + k0 + kk] = u.v;
        }
        {
            int e = tid * 8;
            int n = e >> 5, kk = e & 31;
            *(s16x8*)&Ws[n][kk] = *(const s16x8*)&WcT[(size_t)(colBase + n) * D + k0 + kk];
        }
        __syncthreads();
        s16x8 a[4], b[2];
#pragma unroll
        for (int i = 0; i < 4; i++) a[i] = *(const s16x8*)&As[wr * 64 + i * 16 + lr][lk];
#pragma unroll
        for (int j = 0; j < 2; j++) b[j] = *(const s16x8*)&Ws[wc * 32 + j * 16 + lr][lk];
#pragma unroll
        for (int i = 0; i < 4; i++)
#pragma unroll
            for (int j = 0; j < 2; j++)
                acc[i][j] = __builtin_amdgcn_mfma_f32_16x16x32_bf16(a[i], b[j], acc[i][j], 0, 0, 0);
        __syncthreads();
    }

    if (colBase < 256) {
#pragma unroll
        for (int i = 0; i < 4; i++)
#pragma unroll
            for (int j = 0; j < 2; j++) {
                int col = colBase + wc * 32 + j * 16 + lr;
                float bval = cb[col];
#pragma unroll
                for (int t = 0; t < 4; t++) {
                    int row = rowBase + wr * 64 + i * 16 + g * 4 + t;
                    qkv[(size_t)row * D2 + col] = __float2bfloat16(acc[i][j][t] + bval);
                }
            }
    } else {
#pragma unroll
        for (int i = 0; i < 4; i++)
#pragma unroll
            for (int j = 0; j < 2; j++) {
                int cl = wc * 32 + j * 16 + lr;
                float bval = cb[colBase + cl];
#pragma unroll
                for (int t = 0; t < 4; t++)
                    T[wr * 64 + i * 16 + g * 4 + t][cl] = __float2bfloat16(acc[i][j][t] + bval);
            }
        __syncthreads();
        int hh = (colBase - 256) >> 6;
        int b_ = rowBase >> 11, n0 = rowBase & (N - 1);
        int slot = (z ? 0 : 8) + b_ * H + hh;
        int dh = tid >> 2, nn0 = (tid & 3) * 32;
        alignas(16) __hip_bfloat16 tmp[32];
#pragma unroll
        for (int u = 0; u < 32; u++) tmp[u] = T[nn0 + u][dh];
        __hip_bfloat16* dst = vT + ((size_t)slot * DH + dh) * N + n0 + nn0;
#pragma unroll
        for (int u8 = 0; u8 < 4; u8++)
            *(s16x8*)&dst[u8 * 8] = *(s16x8*)&tmp[u8 * 8];
    }
}

// ---------------- weight prep (transposes + Wo@W1_bot fold, one kernel) ----------------
__device__ void transpose_tile(const float* W, int ldw, __hip_bfloat16* WT, int ldt,
                               int n0, int k0, float scale)
{
    __shared__ float T[32][33];
    int t = threadIdx.x;
    int r = t >> 3, c = (t & 7) * 4;
    float4 v = *(const float4*)&W[(size_t)(k0 + r) * ldw + n0 + c];
    T[r][c] = v.x; T[r][c + 1] = v.y; T[r][c + 2] = v.z; T[r][c + 3] = v.w;
    __syncthreads();
    __hip_bfloat16* dst = &WT[(size_t)(n0 + r) * ldt + k0 + c];
    dst[0] = __float2bfloat16(T[c][r] * scale);
    dst[1] = __float2bfloat16(T[c + 1][r] * scale);
    dst[2] = __float2bfloat16(T[c + 2][r] * scale);
    dst[3] = __float2bfloat16(T[c + 3][r] * scale);
}

__global__ __launch_bounds__(256) void prep_weights(
    const float* Wqk, const float* Wv, const float* Wo,
    const float* W1, const float* W2,
    const float* bqk, const float* bv, const float* b1, const float* bo,
    __hip_bfloat16* WcT, __hip_bfloat16* W1cT, __hip_bfloat16* W2T,
    float* cb, float* cb2)
{
    int blk = blockIdx.x;
    if (blk < 64) {
        int nT = blk & 7, kT = blk >> 3;
        transpose_tile(Wqk, 256, WcT, 256, nT * 32, kT * 32, SCL);
    } else if (blk < 128) {
        int t = blk - 64; int nT = t & 7, kT = t >> 3;
        transpose_tile(Wv, 256, WcT + 256 * 256, 256, nT * 32, kT * 32, 1.f);
    } else if (blk < 256) {
        int t = blk - 128; int nT = t & 15, kT = t >> 4;   // W1 top half: k < 256
        transpose_tile(W1, 512, W1cT, 512, nT * 32, kT * 32, 1.f);
    } else if (blk < 384) {
        int t = blk - 256; int nT = t & 7, kT = t >> 3;
        transpose_tile(W2, 256, W2T, 512, nT * 32, kT * 32, 1.f);
    } else if (blk < 416) {
        // F = Wo @ W1_bot  ->  W1cT[n][256+k] = F[k][n]
        __shared__ float As[64][17];
        __shared__ float Bs[64][17];
        int t2 = blk - 384;
        int n0 = (t2 & 7) * 64, k0 = (t2 >> 3) * 64;
        int tx = threadIdx.x & 15, ty = threadIdx.x >> 4;
        float acc[4][4] = {};
        for (int c0 = 0; c0 < 256; c0 += 16) {
#pragma unroll
            for (int it = 0; it < 4; it++) {
                int idx = threadIdx.x + it * 256;
                int n = idx & 63, c = idx >> 6;
                As[n][c] = W1[(size_t)(256 + c0 + c) * 512 + n0 + n];
            }
#pragma unroll
            for (int it = 0; it < 4; it++) {
                int idx = threadIdx.x + it * 256;
                int k = idx >> 4, c = idx & 15;
                Bs[k][c] = Wo[(size_t)(k0 + k) * 256 + c0 + c];
            }
            __syncthreads();
#pragma unroll
            for (int c = 0; c < 16; c++) {
                float av[4], bv2[4];
#pragma unroll
                for (int i = 0; i < 4; i++) av[i] = As[ty + i * 16][c];
#pragma unroll
                for (int j = 0; j < 4; j++) bv2[j] = Bs[tx + j * 16][c];
#pragma unroll
                for (int i = 0; i < 4; i++)
#pragma unroll
                    for (int j = 0; j < 4; j++) acc[i][j] += av[i] * bv2[j];
            }
            __syncthreads();
        }
#pragma unroll
        for (int i = 0; i < 4; i++)
#pragma unroll
            for (int j = 0; j < 4; j++)
                W1cT[(size_t)(n0 + ty + i * 16) * 512 + 256 + k0 + tx + j * 16] =
                    __float2bfloat16(acc[i][j]);
    } else if (blk < 418) {
        int n = (blk - 416) * 256 + threadIdx.x;
        float s = b1[n];
        for (int c = 0; c < 256; c++) s += bo[c] * W1[(size_t)(256 + c) * 512 + n];
        cb2[n] = s;
    } else {
        int t = threadIdx.x;
        cb[t] = SCL * bqk[t];
        cb[256 + t] = bv[t];
    }
}

// =======================================================================
// fused two-pass attention (LDS-staged K, direct f32 attn stores):
// pass1: sim -> per-lane partial sums; pass2: p=exp*inv -> direct store + P@V.
// Pfb is wave-local (PV A-fragments only) -> 1 barrier per tile.
// =======================================================================
__global__ __launch_bounds__(256) void fused_attn_av(
    const __hip_bfloat16* __restrict__ qkv0, const __hip_bfloat16* __restrict__ qkv1,
    const float* __restrict__ cm0, const float* __restrict__ cm1,
    const __hip_bfloat16* __restrict__ vT,
    float* __restrict__ attn01, float* __restrict__ attn10,
    __hip_bfloat16* __restrict__ xc0, __hip_bfloat16* __restrict__ xc1)
{
    __shared__ __hip_bfloat16 Kt[128][72];
    __shared__ __hip_bfloat16 Pfb[64][136];
    __shared__ float okm[2048];

    const int tid = threadIdx.x;
    int l = blockIdx.x;
    int xcd = l & 7, idx = l >> 3;
    int zz = xcd * 2 + (idx >> 5);
    int xb = idx & 31;
    int dir = zz >> 3, bh = zz & 7;
    int b = bh >> 2, h = bh & 3;

    const __hip_bfloat16* qQ = (dir ? qkv1 : qkv0) + (size_t)b * N * D2 + h * DH;
    const __hip_bfloat16* qK = (dir ? qkv0 : qkv1) + (size_t)b * N * D2 + h * DH;
    const float* cmK = (dir ? cm0 : cm1) + b * N;
    const __hip_bfloat16* vslot = vT + (size_t)((dir ? 8 : 0) + bh) * DH * N;
    float* attnOut = (dir ? attn10 : attn01) + (size_t)bh * N * N;
    __hip_bfloat16* mOut = (dir ? xc1 : xc0) + (size_t)b * N * D2 + 256 + h * DH;

    const int i0 = xb * 64;
    const int lane = tid & 63, w = tid >> 6;
    const int lr = lane & 15, g = lane >> 4;

    // Q fragments in registers (row = w*16+lr)
    s16x8 a0 = *(const s16x8*)&qQ[(size_t)(i0 + w * 16 + lr) * D2 + g * 8];
    s16x8 a1 = *(const s16x8*)&qQ[(size_t)(i0 + w * 16 + lr) * D2 + 32 + g * 8];

    // key mask staged once
#pragma unroll
    for (int it = 0; it < 8; it++) okm[tid + it * 256] = cmK[tid + it * 256];

    s16x8 kreg[4];
    auto loadK = [&](int jt) {
        const int kk0 = jt * 128;
#pragma unroll
        for (int c = 0; c < 4; c++) {
            int e = (tid + c * 256) * 8;
            kreg[c] = *(const s16x8*)&qK[(size_t)(kk0 + (e >> 6)) * D2 + (e & 63)];
        }
    };
    auto writeK = [&]() {
#pragma unroll
        for (int c = 0; c < 4; c++) {
            int e = (tid + c * 256) * 8;
            *(s16x8*)&Kt[e >> 6][e & 63] = kreg[c];
        }
    };

    // ---------------- PASS 1: row sums (no max) ----------------
    float sp[4] = { 0.f, 0.f, 0.f, 0.f };
    loadK(0);
    for (int jt = 0; jt < 16; jt++) {
        writeK();
        __syncthreads();
        if (jt < 15) loadK(jt + 1);

        f32x4 accs[8] = {};
#pragma unroll
        for (int j = 0; j < 8; j++) {
            s16x8 bb = *(const s16x8*)&Kt[j * 16 + lr][g * 8];
            accs[j] = __builtin_amdgcn_mfma_f32_16x16x32_bf16(a0, bb, accs[j], 0, 0, 0);
        }
#pragma unroll
        for (int j = 0; j < 8; j++) {
            s16x8 bb = *(const s16x8*)&Kt[j * 16 + lr][32 + g * 8];
            accs[j] = __builtin_amdgcn_mfma_f32_16x16x32_bf16(a1, bb, accs[j], 0, 0, 0);
        }
        const int k0 = jt * 128;
#pragma unroll
        for (int j = 0; j < 8; j++) {
            bool ok = okm[k0 + j * 16 + lr] >= ALPHA_DIV;
#pragma unroll
            for (int t = 0; t < 4; t++)
                if (ok) sp[t] += __expf(accs[j][t]);
        }
        __syncthreads();
    }
    float inv[4];
#pragma unroll
    for (int t = 0; t < 4; t++) {
#pragma unroll
        for (int off = 1; off <= 8; off <<= 1) sp[t] += __shfl_xor(sp[t], off);
        inv[t] = 1.f / sp[t];
    }

    // ---------------- PASS 2 ----------------
    f32x4 acc_o[4] = {};
    loadK(0);
    for (int jt = 0; jt < 16; jt++) {
        writeK();
        __syncthreads();
        if (jt < 15) loadK(jt + 1);
        const int k0 = jt * 128;

        // V fragments from global (L2-resident panel)
        s16x8 vf[4][4];
#pragma unroll
        for (int ks = 0; ks < 4; ks++)
#pragma unroll
            for (int j = 0; j < 4; j++)
                vf[ks][j] = *(const s16x8*)&vslot[(size_t)(j * 16 + lr) * N + k0 + ks * 32 + g * 8];

        f32x4 accs[8] = {};
#pragma unroll
        for (int j = 0; j < 8; j++) {
            s16x8 bb = *(const s16x8*)&Kt[j * 16 + lr][g * 8];
            accs[j] = __builtin_amdgcn_mfma_f32_16x16x32_bf16(a0, bb, accs[j], 0, 0, 0);
        }
#pragma unroll
        for (int j = 0; j < 8; j++) {
            s16x8 bb = *(const s16x8*)&Kt[j * 16 + lr][32 + g * 8];
            accs[j] = __builtin_amdgcn_mfma_f32_16x16x32_bf16(a1, bb, accs[j], 0, 0, 0);
        }

        // normalize -> direct f32 attn store (16 consecutive lanes = 64B
        // segments; each row gets 512B contiguous per tile) + Pfb bf16
        // (wave-local rows, PV A-fragment only)
#pragma unroll
        for (int j = 0; j < 8; j++) {
            bool ok = okm[k0 + j * 16 + lr] >= ALPHA_DIV;
#pragma unroll
            for (int t = 0; t < 4; t++) {
                float pv = ok ? __expf(accs[j][t]) * inv[t] : 0.f;
                Pfb[w * 16 + g * 4 + t][j * 16 + lr] = __float2bfloat16(pv);
                attnOut[(size_t)(i0 + w * 16 + g * 4 + t) * N + k0 + j * 16 + lr] = pv;
            }
        }

        // P@V (Pfb reads are wave-local: rows w*16..w*16+15)
#pragma unroll
        for (int ks = 0; ks < 4; ks++) {
            s16x8 pa = *(const s16x8*)&Pfb[w * 16 + lr][ks * 32 + g * 8];
#pragma unroll
            for (int j = 0; j < 4; j++)
                acc_o[j] = __builtin_amdgcn_mfma_f32_16x16x32_bf16(pa, vf[ks][j], acc_o[j], 0, 0, 0);
        }
        __syncthreads();
    }

    // epilogue: O -> xc right half via LDS (reuse Pfb; cross-wave -> barrier)
    __hip_bfloat16* Ob = (__hip_bfloat16*)Pfb;
#pragma unroll
    for (int j = 0; j < 4; j++)
#pragma unroll
        for (int t = 0; t < 4; t++)
            Ob[(w * 16 + g * 4 + t) * 136 + j * 16 + lr] = __float2bfloat16(acc_o[j][t]);
    __syncthreads();
    {
        int row = tid >> 2, c0 = (tid & 3) * 16;
        *(s16x8*)&mOut[(size_t)(i0 + row) * D2 + c0]     = *(const s16x8*)&Ob[row * 136 + c0];
        *(s16x8*)&mOut[(size_t)(i0 + row) * D2 + c0 + 8] = *(const s16x8*)&Ob[row * 136 + c0 + 8];
    }
}

// =======================================================================
// FFN tail fused: h = xc@W1cT + cb2; LN; GELU; out = Hs@W2T + b2 + x.
// One block = 32 rows of one stream. grid (128, 2).
// =======================================================================
#define HS_LD 528
__global__ __launch_bounds__(256) void ffn_tail(
    const __hip_bfloat16* __restrict__ xc0, const __hip_bfloat16* __restrict__ xc1,
    const __hip_bfloat16* __restrict__ W1T, const float* __restrict__ b1,
    const float* __restrict__ lng, const float* __restrict__ lnb,
    const __hip_bfloat16* __restrict__ W2T, const float* __restrict__ b2,
    const float* __restrict__ x0, const float* __restrict__ x1,
    float* __restrict__ out0, float* __restrict__ out1)
{
    __shared__ __hip_bfloat16 As[32][BKP];
    __shared__ __hip_bfloat16 WH[512 * BKP];
    __shared__ float redS[4][32], redQ[4][32];

    const __hip_bfloat16* xc = blockIdx.y ? xc1 : xc0;
    const float* xres = blockIdx.y ? x1 : x0;
    float* outp = blockIdx.y ? out1 : out0;
    const int rowBase = blockIdx.x * 32;
    const int tid = threadIdx.x;
    const int w = tid >> 6, lane = tid & 63;
    const int lr = lane & 15, g = lane >> 4, lk = g * 8;

    f32x4 acc[2][8] = {};
    for (int k0 = 0; k0 < D2; k0 += 32) {
        if (tid < 128) {
            int e = tid * 8;
            int r = e >> 5, kk = e & 31;
            *(s16x8*)&As[r][kk] = *(const s16x8*)&xc[(size_t)(rowBase + r) * D2 + k0 + kk];
        }
#pragma unroll
        for (int c = 0; c < 8; c++) {
            int e = (tid + c * 256) * 8;
            int n = e >> 5, kk = e & 31;
            *(s16x8*)&WH[n * BKP + kk] = *(const s16x8*)&W1T[(size_t)n * D2 + k0 + kk];
        }
        __syncthreads();
        s16x8 a[2], b[8];
#pragma unroll
        for (int i = 0; i < 2; i++) a[i] = *(const s16x8*)&As[i * 16 + lr][lk];
#pragma unroll
        for (int j = 0; j < 8; j++) b[j] = *(const s16x8*)&WH[(w * 128 + j * 16 + lr) * BKP + lk];
#pragma unroll
        for (int i = 0; i < 2; i++)
#pragma unroll
            for (int j = 0; j < 8; j++)
                acc[i][j] = __builtin_amdgcn_mfma_f32_16x16x32_bf16(a[i], b[j], acc[i][j], 0, 0, 0);
        __syncthreads();
    }

    float cols_b[8];
#pragma unroll
    for (int j = 0; j < 8; j++) cols_b[j] = b1[w * 128 + j * 16 + lr];
#pragma unroll
    for (int i = 0; i < 2; i++) {
#pragma unroll
        for (int t = 0; t < 4; t++) {
            float s = 0.f, q = 0.f;
#pragma unroll
            for (int j = 0; j < 8; j++) {
                float hv = acc[i][j][t] + cols_b[j];
                acc[i][j][t] = hv;
                s += hv; q += hv * hv;
            }
#pragma unroll
            for (int off = 1; off <= 8; off <<= 1) {
                s += __shfl_xor(s, off);
                q += __shfl_xor(q, off);
            }
            if (lr == 0) {
                int row = i * 16 + g * 4 + t;
                redS[w][row] = s; redQ[w][row] = q;
            }
        }
    }
    __syncthreads();

    __hip_bfloat16* Hs = WH;
    float gcol[8], bcol[8];
#pragma unroll
    for (int j = 0; j < 8; j++) {
        gcol[j] = lng[w * 128 + j * 16 + lr];
        bcol[j] = lnb[w * 128 + j * 16 + lr];
    }
#pragma unroll
    for (int i = 0; i < 2; i++) {
#pragma unroll
        for (int t = 0; t < 4; t++) {
            int row = i * 16 + g * 4 + t;
            float sum = redS[0][row] + redS[1][row] + redS[2][row] + redS[3][row];
            float sq  = redQ[0][row] + redQ[1][row] + redQ[2][row] + redQ[3][row];
            float mu = sum * (1.f / 512.f);
            float var = sq * (1.f / 512.f) - mu * mu;
            float rstd = rsqrtf(var + LN_EPS);
#pragma unroll
            for (int j = 0; j < 8; j++) {
                float y = (acc[i][j][t] - mu) * rstd * gcol[j] + bcol[j];
                float ge = 0.5f * y * (1.f + erff(y * 0.70710678118654752f));
                Hs[row * HS_LD + w * 128 + j * 16 + lr] = __float2bfloat16(ge);
            }
        }
    }
    __syncthreads();

    f32x4 acc2[2][4] = {};
    for (int k0 = 0; k0 < D2; k0 += 32) {
        s16x8 a[2], b[4];
#pragma unroll
        for (int i = 0; i < 2; i++)
            a[i] = *(const s16x8*)&Hs[(i * 16 + lr) * HS_LD + k0 + lk];
#pragma unroll
        for (int j = 0; j < 4; j++)
            b[j] = *(const s16x8*)&W2T[(size_t)(w * 64 + j * 16 + lr) * D2 + k0 + lk];
#pragma unroll
        for (int i = 0; i < 2; i++)
#pragma unroll
            for (int j = 0; j < 4; j++)
                acc2[i][j] = __builtin_amdgcn_mfma_f32_16x16x32_bf16(a[i], b[j], acc2[i][j], 0, 0, 0);
    }
#pragma unroll
    for (int i = 0; i < 2; i++) {
#pragma unroll
        for (int j = 0; j < 4; j++) {
            int col = w * 64 + j * 16 + lr;
            float bval = b2[col];
#pragma unroll
            for (int t = 0; t < 4; t++) {
                int row = rowBase + i * 16 + g * 4 + t;
                outp[(size_t)row * D + col] =
                    acc2[i][j][t] + bval + xres[(size_t)row * D + col];
            }
        }
    }
}

extern "C" void kernel_launch(void* const* d_in, const int* in_sizes, int n_in,
                              void* d_out, int out_size, void* d_ws, size_t ws_size,
                              hipStream_t stream) {
    const float* x0  = (const float*)d_in[0];
    const float* x1  = (const float*)d_in[1];
    const float* cm0 = (const float*)d_in[2];
    const float* cm1 = (const float*)d_in[3];
    const float* Wqk = (const float*)d_in[4]; const float* bqk = (const float*)d_in[5];
    const float* Wv  = (const float*)d_in[6]; const float* bv  = (const float*)d_in[7];
    const float* Wo  = (const float*)d_in[8]; const float* bo  = (const float*)d_in[9];
    const float* W1  = (const float*)d_in[10]; const float* b1 = (const float*)d_in[11];
    const float* lng = (const float*)d_in[12]; const float* lnb = (const float*)d_in[13];
    const float* W2  = (const float*)d_in[14]; const float* b2 = (const float*)d_in[15];

    float* out = (float*)d_out;
    char* p = (char*)d_ws;

    const size_t XSZ = (size_t)B * N * D;
    auto alloc = [&](size_t bytes) { char* r = p; p += (bytes + 255) & ~255ull; return r; };
    __hip_bfloat16* qkv0 = (__hip_bfloat16*)alloc((size_t)B * N * D2 * 2);
    __hip_bfloat16* qkv1 = (__hip_bfloat16*)alloc((size_t)B * N * D2 * 2);
    __hip_bfloat16* vT   = (__hip_bfloat16*)alloc((size_t)16 * DH * N * 2);
    __hip_bfloat16* xc0  = (__hip_bfloat16*)alloc((size_t)B * N * D2 * 2);
    __hip_bfloat16* xc1  = (__hip_bfloat16*)alloc((size_t)B * N * D2 * 2);
    __hip_bfloat16* WcT  = (__hip_bfloat16*)alloc(512 * 256 * 2);
    __hip_bfloat16* W1cT = (__hip_bfloat16*)alloc(512 * 512 * 2);
    __hip_bfloat16* W2T  = (__hip_bfloat16*)alloc(256 * 512 * 2);
    float* cb            = (float*)alloc(512 * 4);
    float* cb2           = (float*)alloc(512 * 4);

    float* out0 = out;
    float* out1 = out + XSZ;
    float* attn01 = out + 2 * XSZ;
    float* attn10 = attn01 + (size_t)BH * N * N;

    dim3 blk(256);

    prep_weights<<<419, blk, 0, stream>>>(Wqk, Wv, Wo, W1, W2, bqk, bv, b1, bo,
                                          WcT, W1cT, W2T, cb, cb2);

    proj_kernel<<<dim3(8, 32, 2), blk, 0, stream>>>(
        x0, x1, WcT, cb, qkv0, qkv1, vT, xc0, xc1);

    fused_attn_av<<<512, blk, 0, stream>>>(qkv0, qkv1, cm0, cm1, vT,
        attn01, attn10, xc0, xc1);

    ffn_tail<<<dim3(128, 2), blk, 0, stream>>>(
        xc0, xc1, W1cT, cb2, lng, lnb, W2T, b2, x0, x1, out0, out1);
}